// Round 1
// baseline (240.198 us; speedup 1.0000x reference)
//
#include <hip/hip_runtime.h>
#include <hip/hip_cooperative_groups.h>
#include <stdint.h>

namespace cg = cooperative_groups;
typedef unsigned int u32;

// Single cooperative kernel. Phase 1: bit-sliced vote counts (6 planes) held in
// REGISTERS (no planes spill to HBM). grid.sync() carries them across the
// global popcount reduction needed for the threshold. Phase 2: threshold +
// bitwise compare + XNOR + store, ratio via fenced last-block-done pattern.
// Exactly pgs threads (512 blocks x 256), 2 blocks/CU -> co-resident.
__global__ __launch_bounds__(256) void k_fused(
    const int* __restrict__ flip,
    const int* __restrict__ weights,
    u32* __restrict__ popslot,        // [nblk] per-block flip popcounts
    u32* __restrict__ acc,            // acc[0]=mask popcount, acc[1]=done count
    const float* __restrict__ vote_p_max,
    const int* __restrict__ n_votes_p,
    float* __restrict__ out,
    int npos, int nvotes, int nblk)
{
    cg::grid_group grid = cg::this_grid();
    const int pgs = npos >> 2;
    const int t = blockIdx.x * blockDim.x + threadIdx.x;

    // Zero the ratio accumulators before the grid sync (workspace is poisoned;
    // visibility to all XCDs guaranteed by the fence+sync below).
    if (blockIdx.x == 0 && threadIdx.x == 0) { acc[0] = 0u; acc[1] = 0u; }

    // ---- Phase 1: count --------------------------------------------------
    u32 p0 = 0, p1 = 0, p2 = 0, p3 = 0, p4 = 0, p5 = 0;
    u32 pop = 0;
    if (t < pgs) {
        const int4* fp = (const int4*)flip + t;
        int v = 0;
        for (; v + 8 <= nvotes; v += 8) {
            int4 x[8];
#pragma unroll
            for (int j = 0; j < 8; ++j)
                x[j] = fp[(size_t)(v + j) * pgs];    // 8 coalesced 16B loads in flight
#pragma unroll
            for (int j = 0; j < 8; ++j) {
                u32 w = ((u32)x[j].x & 0xFFu) | (((u32)x[j].y & 0xFFu) << 8)
                      | (((u32)x[j].z & 0xFFu) << 16) | (((u32)x[j].w & 0xFFu) << 24);
                pop += __popc(w);
                u32 c = w, tn;                       // ripple +1 through 6 planes
                tn = p0 & c; p0 ^= c; c = tn;
                tn = p1 & c; p1 ^= c; c = tn;
                tn = p2 & c; p2 ^= c; c = tn;
                tn = p3 & c; p3 ^= c; c = tn;
                tn = p4 & c; p4 ^= c; c = tn;
                p5 ^= c;
            }
        }
        for (; v < nvotes; ++v) {                    // tail (unused for nvotes=32)
            int4 x = fp[(size_t)v * pgs];
            u32 w = ((u32)x.x & 0xFFu) | (((u32)x.y & 0xFFu) << 8)
                  | (((u32)x.z & 0xFFu) << 16) | (((u32)x.w & 0xFFu) << 24);
            pop += __popc(w);
            u32 c = w, tn;
            tn = p0 & c; p0 ^= c; c = tn;
            tn = p1 & c; p1 ^= c; c = tn;
            tn = p2 & c; p2 ^= c; c = tn;
            tn = p3 & c; p3 ^= c; c = tn;
            tn = p4 & c; p4 ^= c; c = tn;
            p5 ^= c;
        }
    }
    // block-reduce pop -> popslot[blockIdx]
    for (int off = 32; off > 0; off >>= 1)
        pop += __shfl_down(pop, off, 64);
    __shared__ u32 sred[4];
    __shared__ float s_thresh;
    const int wid = threadIdx.x >> 6;
    if ((threadIdx.x & 63) == 0) sred[wid] = pop;
    __syncthreads();
    if (threadIdx.x == 0)
        popslot[blockIdx.x] = sred[0] + sred[1] + sred[2] + sred[3];

    __threadfence();       // release: popslot + acc zeros out of this XCD's L2
    grid.sync();
    __threadfence();       // acquire: invalidate stale lines before re-reading

    // ---- Phase 2: threshold (block-redundant 2KB sum) --------------------
    u32 s = 0;
    for (int i = threadIdx.x; i < nblk; i += blockDim.x) s += popslot[i];
    for (int off = 32; off > 0; off >>= 1) s += __shfl_down(s, off, 64);
    if ((threadIdx.x & 63) == 0) sred[wid] = s;
    __syncthreads();
    if (threadIdx.x == 0) {
        u32 total = sred[0] + sred[1] + sred[2] + sred[3];
        float nv = (float)n_votes_p[0];
        float mean = (float)((double)total / ((double)npos * 8.0));
        s_thresh = fmaxf(vote_p_max[0] * nv, mean);  // == max(p, mean/nv)*nv
    }
    __syncthreads();
    const float thresh = s_thresh;

    // ---- Phase 2b: apply from register planes ----------------------------
    pop = 0;
    if (t < pgs) {
        int K = (int)floorf(thresh) + 1;   // count > thresh  <=>  count >= K
        if (K < 0) K = 0;
        if (K > 64) K = 64;
        u32 Kp = (u32)(64 - K);            // carry-out of (count + Kp) <=> count >= K
        u32 carry = (Kp & 1u)  ? p0 : 0u;  // ripple carry, K wave-uniform
        carry = (Kp & 2u)  ? (p1 | carry) : (p1 & carry);
        carry = (Kp & 4u)  ? (p2 | carry) : (p2 & carry);
        carry = (Kp & 8u)  ? (p3 | carry) : (p3 & carry);
        carry = (Kp & 16u) ? (p4 | carry) : (p4 & carry);
        carry = (Kp & 32u) ? (p5 | carry) : (p5 & carry);
        u32 mask = (K == 0) ? 0xFFFFFFFFu : carry;
        int4 wv = ((const int4*)weights)[t];
        u32 ww = ((u32)wv.x & 0xFFu) | (((u32)wv.y & 0xFFu) << 8)
               | (((u32)wv.z & 0xFFu) << 16) | (((u32)wv.w & 0xFFu) << 24);
        u32 xn = ~(ww ^ mask);
        ((float4*)out)[t] = make_float4((float)(xn & 0xFFu),
                                        (float)((xn >> 8) & 0xFFu),
                                        (float)((xn >> 16) & 0xFFu),
                                        (float)((xn >> 24) & 0xFFu));
        pop = __popc(mask);
    }
    for (int off = 32; off > 0; off >>= 1)
        pop += __shfl_down(pop, off, 64);
    __syncthreads();                        // sred reuse
    if ((threadIdx.x & 63) == 0) sred[wid] = pop;
    __syncthreads();
    if (threadIdx.x == 0) {
        u32 blockpop = sred[0] + sred[1] + sred[2] + sred[3];
        atomicAdd(&acc[0], blockpop);       // device-scope by default
        __threadfence();                    // order acc[0] add before done-count
        u32 old = atomicAdd(&acc[1], 1u);
        if (old == (u32)(nblk - 1)) {       // last block done: all adds visible
            __threadfence();
            u32 mp = atomicAdd(&acc[0], 0u);  // coherent read via RMW
            out[npos] = (float)((double)mp / ((double)npos * 8.0));
        }
    }
}

extern "C" void kernel_launch(void* const* d_in, const int* in_sizes, int n_in,
                              void* d_out, int out_size, void* d_ws, size_t ws_size,
                              hipStream_t stream) {
    const int* weights      = (const int*)d_in[0];   // 2048*256 bytes, one per int32
    const int* flip         = (const int*)d_in[1];   // 32*2048*256, one byte per int32
    const int* n_votes_p    = (const int*)d_in[2];
    const float* vote_p_max = (const float*)d_in[3];

    int npos   = in_sizes[0];               // 524288 byte positions
    int nvotes = in_sizes[1] / in_sizes[0]; // 32
    int pgs    = npos / 4;                  // 131072 position groups

    int block = 256;
    int gx = (pgs + block - 1) / block;     // 512 blocks = 2/CU, co-resident

    // ws layout (no memset: popslot fully written before read; acc zeroed
    // in-kernel before the grid sync):
    u32* popslot = (u32*)d_ws;
    u32* acc     = (u32*)((char*)d_ws + 16384);  // separate cache lines
    float* out_f = (float*)d_out;

    void* args[] = { (void*)&flip, (void*)&weights, (void*)&popslot, (void*)&acc,
                     (void*)&vote_p_max, (void*)&n_votes_p, (void*)&out_f,
                     (void*)&npos, (void*)&nvotes, (void*)&gx };
    (void)hipLaunchCooperativeKernel((void*)k_fused, dim3(gx), dim3(block),
                                     args, 0, stream);
}

// Round 2
// 114.715 us; speedup vs baseline: 2.0939x; 2.0939x over previous
//
#include <hip/hip_runtime.h>
#include <stdint.h>

typedef unsigned int u32;

// Kernel 1: single-pass bit-sliced vote counts (round-0 proven structure).
// One thread per 4 byte-positions (= 32 bit-positions packed in u32 lanes).
// All 32 votes accumulated into a 6-plane bit-sliced counter (count <= 32).
// 8 int4 loads kept in flight; no atomics, no fences, no memset.
// Also zeroes the ratio accumulators for k_apply (kernel boundary = visibility).
__global__ __launch_bounds__(256) void k_count(const int* __restrict__ flip,
                                               u32* __restrict__ planes,
                                               u32* __restrict__ popslot,
                                               u32* __restrict__ acc,
                                               int npos, int nvotes) {
    int t = blockIdx.x * blockDim.x + threadIdx.x;   // position-group id
    int pgs = npos >> 2;
    if (blockIdx.x == 0 && threadIdx.x == 0) { acc[0] = 0u; acc[1] = 0u; }
    u32 pop = 0;
    if (t < pgs) {
        const int4* fp = (const int4*)flip + t;
        u32 p0 = 0, p1 = 0, p2 = 0, p3 = 0, p4 = 0, p5 = 0;
        int v = 0;
        for (; v + 8 <= nvotes; v += 8) {
            int4 x[8];
#pragma unroll
            for (int j = 0; j < 8; ++j)
                x[j] = fp[(size_t)(v + j) * pgs];    // 8 coalesced 16B loads in flight
#pragma unroll
            for (int j = 0; j < 8; ++j) {
                u32 w = ((u32)x[j].x & 0xFFu) | (((u32)x[j].y & 0xFFu) << 8)
                      | (((u32)x[j].z & 0xFFu) << 16) | (((u32)x[j].w & 0xFFu) << 24);
                pop += __popc(w);
                u32 c = w, tn;                       // ripple +1 through 6 planes
                tn = p0 & c; p0 ^= c; c = tn;
                tn = p1 & c; p1 ^= c; c = tn;
                tn = p2 & c; p2 ^= c; c = tn;
                tn = p3 & c; p3 ^= c; c = tn;
                tn = p4 & c; p4 ^= c; c = tn;
                p5 ^= c;
            }
        }
        for (; v < nvotes; ++v) {                    // tail (unused for nvotes=32)
            int4 x = fp[(size_t)v * pgs];
            u32 w = ((u32)x.x & 0xFFu) | (((u32)x.y & 0xFFu) << 8)
                  | (((u32)x.z & 0xFFu) << 16) | (((u32)x.w & 0xFFu) << 24);
            pop += __popc(w);
            u32 c = w, tn;
            tn = p0 & c; p0 ^= c; c = tn;
            tn = p1 & c; p1 ^= c; c = tn;
            tn = p2 & c; p2 ^= c; c = tn;
            tn = p3 & c; p3 ^= c; c = tn;
            tn = p4 & c; p4 ^= c; c = tn;
            p5 ^= c;
        }
        planes[t]                   = p0;            // SoA: 6 coalesced 4B stores
        planes[(size_t)pgs + t]     = p1;
        planes[(size_t)2*pgs + t]   = p2;
        planes[(size_t)3*pgs + t]   = p3;
        planes[(size_t)4*pgs + t]   = p4;
        planes[(size_t)5*pgs + t]   = p5;
    }
    for (int off = 32; off > 0; off >>= 1)
        pop += __shfl_down(pop, off, 64);
    __shared__ u32 sred[4];
    int wid = threadIdx.x >> 6;
    if ((threadIdx.x & 63) == 0) sred[wid] = pop;
    __syncthreads();
    if (threadIdx.x == 0)
        popslot[blockIdx.x] = sred[0] + sred[1] + sred[2] + sred[3];  // no atomic
}

// Kernel 2: block-redundant threshold from popslots (2KB, L2-hit), bitwise
// threshold compare across 32 positions at once, XNOR with weights, float4
// store. Ratio fused in via the fenced last-block-done pattern (validated
// round 1: absmax=0): per-block mask popcount -> device atomic, last block
// to arrive reads the total and writes out[npos].
__global__ __launch_bounds__(256) void k_apply(const int* __restrict__ weights,
                                               const u32* __restrict__ planes,
                                               const u32* __restrict__ popslot,
                                               const float* __restrict__ vote_p_max,
                                               const int* __restrict__ n_votes_p,
                                               float* __restrict__ out,
                                               u32* __restrict__ acc,
                                               int npos, int nblk) {
    int pgs = npos >> 2;
    __shared__ u32 sred[4];
    __shared__ float s_thresh;
    // block-redundant total: sum popslot[0..nblk)
    u32 s = 0;
    for (int i = threadIdx.x; i < nblk; i += blockDim.x) s += popslot[i];
    for (int off = 32; off > 0; off >>= 1) s += __shfl_down(s, off, 64);
    int wid = threadIdx.x >> 6;
    if ((threadIdx.x & 63) == 0) sred[wid] = s;
    __syncthreads();
    if (threadIdx.x == 0) {
        u32 total = sred[0] + sred[1] + sred[2] + sred[3];
        float nv = (float)n_votes_p[0];
        float mean = (float)((double)total / ((double)npos * 8.0));
        s_thresh = fmaxf(vote_p_max[0] * nv, mean);  // == max(p,mean/nv)*nv
    }
    __syncthreads();
    float thresh = s_thresh;
    int t = blockIdx.x * blockDim.x + threadIdx.x;
    u32 pop = 0;
    if (t < pgs) {
        int K = (int)floorf(thresh) + 1;   // count > thresh  <=>  count >= K
        if (K < 0) K = 0;
        if (K > 64) K = 64;
        u32 Kp = (u32)(64 - K);            // carry-out of (count + Kp) <=> count >= K
        u32 a0 = planes[t];
        u32 a1 = planes[(size_t)pgs + t];
        u32 a2 = planes[(size_t)2*pgs + t];
        u32 a3 = planes[(size_t)3*pgs + t];
        u32 a4 = planes[(size_t)4*pgs + t];
        u32 a5 = planes[(size_t)5*pgs + t];
        u32 carry = (Kp & 1u)  ? a0 : 0u;  // ripple carry, K wave-uniform
        carry = (Kp & 2u)  ? (a1 | carry) : (a1 & carry);
        carry = (Kp & 4u)  ? (a2 | carry) : (a2 & carry);
        carry = (Kp & 8u)  ? (a3 | carry) : (a3 & carry);
        carry = (Kp & 16u) ? (a4 | carry) : (a4 & carry);
        carry = (Kp & 32u) ? (a5 | carry) : (a5 & carry);
        u32 mask = (K == 0) ? 0xFFFFFFFFu : carry;
        int4 wv = ((const int4*)weights)[t];
        u32 ww = ((u32)wv.x & 0xFFu) | (((u32)wv.y & 0xFFu) << 8)
               | (((u32)wv.z & 0xFFu) << 16) | (((u32)wv.w & 0xFFu) << 24);
        u32 xn = ~(ww ^ mask);
        ((float4*)out)[t] = make_float4((float)(xn & 0xFFu),
                                        (float)((xn >> 8) & 0xFFu),
                                        (float)((xn >> 16) & 0xFFu),
                                        (float)((xn >> 24) & 0xFFu));
        pop = __popc(mask);
    }
    for (int off = 32; off > 0; off >>= 1)
        pop += __shfl_down(pop, off, 64);
    __syncthreads();                        // sred reuse
    if ((threadIdx.x & 63) == 0) sred[wid] = pop;
    __syncthreads();
    if (threadIdx.x == 0) {
        u32 blockpop = sred[0] + sred[1] + sred[2] + sred[3];
        atomicAdd(&acc[0], blockpop);       // device-scope by default
        __threadfence();                    // order the pop add before done-count
        u32 old = atomicAdd(&acc[1], 1u);
        if (old == (u32)(nblk - 1)) {       // last block: all adds visible
            __threadfence();
            u32 mp = atomicAdd(&acc[0], 0u);  // coherent read via RMW
            out[npos] = (float)((double)mp / ((double)npos * 8.0));
        }
    }
}

extern "C" void kernel_launch(void* const* d_in, const int* in_sizes, int n_in,
                              void* d_out, int out_size, void* d_ws, size_t ws_size,
                              hipStream_t stream) {
    const int* weights      = (const int*)d_in[0];   // 2048*256 bytes, one per int32
    const int* flip         = (const int*)d_in[1];   // 32*2048*256, one byte per int32
    const int* n_votes_p    = (const int*)d_in[2];
    const float* vote_p_max = (const float*)d_in[3];

    int npos   = in_sizes[0];               // 524288 byte positions
    int nvotes = in_sizes[1] / in_sizes[0]; // 32
    int pgs    = npos / 4;                  // 131072 position groups

    int block = 256;
    int gx = (pgs + block - 1) / block;     // 512 blocks

    // ws layout (no memset needed — popslot fully written before read; acc
    // zeroed by k_count, visible to k_apply via the kernel boundary):
    // [0 .. 4*gx)            popslot
    // [16384 .. 16392)       acc[0]=mask popcount, acc[1]=done counter
    // [65536 .. )            planes: 6 * pgs * 4B = 3 MB
    u32* popslot = (u32*)d_ws;
    u32* acc     = (u32*)((char*)d_ws + 16384);
    u32* planes  = (u32*)((char*)d_ws + 65536);

    k_count<<<gx, block, 0, stream>>>(flip, planes, popslot, acc, npos, nvotes);
    k_apply<<<gx, block, 0, stream>>>(weights, planes, popslot, vote_p_max,
                                      n_votes_p, (float*)d_out, acc, npos, gx);
}

// Round 3
// 114.166 us; speedup vs baseline: 2.1039x; 1.0048x over previous
//
#include <hip/hip_runtime.h>
#include <stdint.h>

typedef unsigned int u32;

// Kernel 1: single-pass bit-sliced vote counts (round-0 proven structure).
// One thread per 4 byte-positions (= 32 bit-positions packed in u32 lanes).
// All 32 votes accumulated into a 6-plane bit-sliced counter (count <= 32).
// 8 int4 loads kept in flight; no atomics, no fences, no memset.
// Also zeroes the ratio accumulators for k_apply; end-of-dispatch release
// makes the zeros globally visible (validated rounds 1-2, absmax=0).
__global__ __launch_bounds__(256) void k_count(const int* __restrict__ flip,
                                               u32* __restrict__ planes,
                                               u32* __restrict__ popslot,
                                               u32* __restrict__ acc,
                                               int npos, int nvotes) {
    int t = blockIdx.x * blockDim.x + threadIdx.x;   // position-group id
    int pgs = npos >> 2;
    if (blockIdx.x == 0 && threadIdx.x == 0) { acc[0] = 0u; acc[1] = 0u; }
    u32 pop = 0;
    if (t < pgs) {
        const int4* fp = (const int4*)flip + t;
        u32 p0 = 0, p1 = 0, p2 = 0, p3 = 0, p4 = 0, p5 = 0;
        int v = 0;
        for (; v + 8 <= nvotes; v += 8) {
            int4 x[8];
#pragma unroll
            for (int j = 0; j < 8; ++j)
                x[j] = fp[(size_t)(v + j) * pgs];    // 8 coalesced 16B loads in flight
#pragma unroll
            for (int j = 0; j < 8; ++j) {
                u32 w = ((u32)x[j].x & 0xFFu) | (((u32)x[j].y & 0xFFu) << 8)
                      | (((u32)x[j].z & 0xFFu) << 16) | (((u32)x[j].w & 0xFFu) << 24);
                pop += __popc(w);
                u32 c = w, tn;                       // ripple +1 through 6 planes
                tn = p0 & c; p0 ^= c; c = tn;
                tn = p1 & c; p1 ^= c; c = tn;
                tn = p2 & c; p2 ^= c; c = tn;
                tn = p3 & c; p3 ^= c; c = tn;
                tn = p4 & c; p4 ^= c; c = tn;
                p5 ^= c;
            }
        }
        for (; v < nvotes; ++v) {                    // tail (unused for nvotes=32)
            int4 x = fp[(size_t)v * pgs];
            u32 w = ((u32)x.x & 0xFFu) | (((u32)x.y & 0xFFu) << 8)
                  | (((u32)x.z & 0xFFu) << 16) | (((u32)x.w & 0xFFu) << 24);
            pop += __popc(w);
            u32 c = w, tn;
            tn = p0 & c; p0 ^= c; c = tn;
            tn = p1 & c; p1 ^= c; c = tn;
            tn = p2 & c; p2 ^= c; c = tn;
            tn = p3 & c; p3 ^= c; c = tn;
            tn = p4 & c; p4 ^= c; c = tn;
            p5 ^= c;
        }
        planes[t]                   = p0;            // SoA: 6 coalesced 4B stores
        planes[(size_t)pgs + t]     = p1;
        planes[(size_t)2*pgs + t]   = p2;
        planes[(size_t)3*pgs + t]   = p3;
        planes[(size_t)4*pgs + t]   = p4;
        planes[(size_t)5*pgs + t]   = p5;
    }
    for (int off = 32; off > 0; off >>= 1)
        pop += __shfl_down(pop, off, 64);
    __shared__ u32 sred[4];
    int wid = threadIdx.x >> 6;
    if ((threadIdx.x & 63) == 0) sred[wid] = pop;
    __syncthreads();
    if (threadIdx.x == 0)
        popslot[blockIdx.x] = sred[0] + sred[1] + sred[2] + sred[3];  // no atomic
}

// Kernel 2: block-redundant threshold from popslots (2KB, L2-hit), bitwise
// threshold compare across 32 positions at once, XNOR with weights, float4
// store. Ratio fused in FENCE-FREE: per-block mask popcount -> device atomic;
// ordering acc[0]-add -> acc[1]-add enforced by a data-dependency wait on the
// first atomic's return value (s_waitcnt, no L2 writeback). Last block to
// arrive reads the completed total via RMW and writes out[npos].
__global__ __launch_bounds__(256) void k_apply(const int* __restrict__ weights,
                                               const u32* __restrict__ planes,
                                               const u32* __restrict__ popslot,
                                               const float* __restrict__ vote_p_max,
                                               const int* __restrict__ n_votes_p,
                                               float* __restrict__ out,
                                               u32* __restrict__ acc,
                                               int npos, int nblk) {
    int pgs = npos >> 2;
    __shared__ u32 sred[4];
    __shared__ float s_thresh;
    // block-redundant total: sum popslot[0..nblk)
    u32 s = 0;
    for (int i = threadIdx.x; i < nblk; i += blockDim.x) s += popslot[i];
    for (int off = 32; off > 0; off >>= 1) s += __shfl_down(s, off, 64);
    int wid = threadIdx.x >> 6;
    if ((threadIdx.x & 63) == 0) sred[wid] = s;
    __syncthreads();
    if (threadIdx.x == 0) {
        u32 total = sred[0] + sred[1] + sred[2] + sred[3];
        float nv = (float)n_votes_p[0];
        float mean = (float)((double)total / ((double)npos * 8.0));
        s_thresh = fmaxf(vote_p_max[0] * nv, mean);  // == max(p,mean/nv)*nv
    }
    __syncthreads();
    float thresh = s_thresh;
    int t = blockIdx.x * blockDim.x + threadIdx.x;
    u32 pop = 0;
    if (t < pgs) {
        int K = (int)floorf(thresh) + 1;   // count > thresh  <=>  count >= K
        if (K < 0) K = 0;
        if (K > 64) K = 64;
        u32 Kp = (u32)(64 - K);            // carry-out of (count + Kp) <=> count >= K
        u32 a0 = planes[t];
        u32 a1 = planes[(size_t)pgs + t];
        u32 a2 = planes[(size_t)2*pgs + t];
        u32 a3 = planes[(size_t)3*pgs + t];
        u32 a4 = planes[(size_t)4*pgs + t];
        u32 a5 = planes[(size_t)5*pgs + t];
        u32 carry = (Kp & 1u)  ? a0 : 0u;  // ripple carry, K wave-uniform
        carry = (Kp & 2u)  ? (a1 | carry) : (a1 & carry);
        carry = (Kp & 4u)  ? (a2 | carry) : (a2 & carry);
        carry = (Kp & 8u)  ? (a3 | carry) : (a3 & carry);
        carry = (Kp & 16u) ? (a4 | carry) : (a4 & carry);
        carry = (Kp & 32u) ? (a5 | carry) : (a5 & carry);
        u32 mask = (K == 0) ? 0xFFFFFFFFu : carry;
        int4 wv = ((const int4*)weights)[t];
        u32 ww = ((u32)wv.x & 0xFFu) | (((u32)wv.y & 0xFFu) << 8)
               | (((u32)wv.z & 0xFFu) << 16) | (((u32)wv.w & 0xFFu) << 24);
        u32 xn = ~(ww ^ mask);
        ((float4*)out)[t] = make_float4((float)(xn & 0xFFu),
                                        (float)((xn >> 8) & 0xFFu),
                                        (float)((xn >> 16) & 0xFFu),
                                        (float)((xn >> 24) & 0xFFu));
        pop = __popc(mask);
    }
    for (int off = 32; off > 0; off >>= 1)
        pop += __shfl_down(pop, off, 64);
    __syncthreads();                        // sred reuse
    if ((threadIdx.x & 63) == 0) sred[wid] = pop;
    __syncthreads();
    if (threadIdx.x == 0) {
        u32 blockpop = sred[0] + sred[1] + sred[2] + sred[3];
        // Atomic 1: contribute mask popcount (performed at coherence point).
        u32 oldpop = atomicAdd(&acc[0], blockpop);
        // Force completion (s_waitcnt on the returned value) BEFORE the done
        // counter bumps — ordering via data dependency, no cache-flush fence.
        asm volatile("" :: "v"(oldpop));
        // Atomic 2: done counter.
        u32 old = atomicAdd(&acc[1], 1u);
        if (old == (u32)(nblk - 1)) {
            // All other blocks' acc[0] adds completed at the coherence point
            // before their acc[1] bumps -> RMW read returns the full total.
            u32 mp = atomicAdd(&acc[0], 0u);
            out[npos] = (float)((double)mp / ((double)npos * 8.0));
        }
    }
}

extern "C" void kernel_launch(void* const* d_in, const int* in_sizes, int n_in,
                              void* d_out, int out_size, void* d_ws, size_t ws_size,
                              hipStream_t stream) {
    const int* weights      = (const int*)d_in[0];   // 2048*256 bytes, one per int32
    const int* flip         = (const int*)d_in[1];   // 32*2048*256, one byte per int32
    const int* n_votes_p    = (const int*)d_in[2];
    const float* vote_p_max = (const float*)d_in[3];

    int npos   = in_sizes[0];               // 524288 byte positions
    int nvotes = in_sizes[1] / in_sizes[0]; // 32
    int pgs    = npos / 4;                  // 131072 position groups

    int block = 256;
    int gx = (pgs + block - 1) / block;     // 512 blocks

    // ws layout (no memset needed — popslot fully written before read; acc
    // zeroed by k_count, visible to k_apply via end-of-dispatch release):
    // [0 .. 4*gx)            popslot
    // [16384 .. 16392)       acc[0]=mask popcount, acc[1]=done counter
    // [65536 .. )            planes: 6 * pgs * 4B = 3 MB
    u32* popslot = (u32*)d_ws;
    u32* acc     = (u32*)((char*)d_ws + 16384);
    u32* planes  = (u32*)((char*)d_ws + 65536);

    k_count<<<gx, block, 0, stream>>>(flip, planes, popslot, acc, npos, nvotes);
    k_apply<<<gx, block, 0, stream>>>(weights, planes, popslot, vote_p_max,
                                      n_votes_p, (float*)d_out, acc, npos, gx);
}

// Round 4
// 104.868 us; speedup vs baseline: 2.2905x; 1.0887x over previous
//
#include <hip/hip_runtime.h>
#include <stdint.h>

typedef unsigned int u32;

// Kernel 1: single-pass bit-sliced vote counts (round-0 proven structure).
// One thread per 4 byte-positions (= 32 bit-positions packed in u32 lanes).
// All 32 votes accumulated into a 6-plane bit-sliced counter (count <= 32).
// 8 int4 loads kept in flight; no atomics, no fences, no memset.
// Planes packed AoS: int4 (p0..p3) + int2 (p4,p5) -> 2 wide coalesced stores
// instead of 6 scalar stores (cuts instructions on the inter-kernel path).
__global__ __launch_bounds__(256) void k_count(const int* __restrict__ flip,
                                               int4* __restrict__ planesA,
                                               int2* __restrict__ planesB,
                                               u32* __restrict__ popslot,
                                               int npos, int nvotes) {
    int t = blockIdx.x * blockDim.x + threadIdx.x;   // position-group id
    int pgs = npos >> 2;
    u32 pop = 0;
    if (t < pgs) {
        const int4* fp = (const int4*)flip + t;
        u32 p0 = 0, p1 = 0, p2 = 0, p3 = 0, p4 = 0, p5 = 0;
        int v = 0;
        for (; v + 8 <= nvotes; v += 8) {
            int4 x[8];
#pragma unroll
            for (int j = 0; j < 8; ++j)
                x[j] = fp[(size_t)(v + j) * pgs];    // 8 coalesced 16B loads in flight
#pragma unroll
            for (int j = 0; j < 8; ++j) {
                u32 w = ((u32)x[j].x & 0xFFu) | (((u32)x[j].y & 0xFFu) << 8)
                      | (((u32)x[j].z & 0xFFu) << 16) | (((u32)x[j].w & 0xFFu) << 24);
                pop += __popc(w);
                u32 c = w, tn;                       // ripple +1 through 6 planes
                tn = p0 & c; p0 ^= c; c = tn;
                tn = p1 & c; p1 ^= c; c = tn;
                tn = p2 & c; p2 ^= c; c = tn;
                tn = p3 & c; p3 ^= c; c = tn;
                tn = p4 & c; p4 ^= c; c = tn;
                p5 ^= c;
            }
        }
        for (; v < nvotes; ++v) {                    // tail (unused for nvotes=32)
            int4 x = fp[(size_t)v * pgs];
            u32 w = ((u32)x.x & 0xFFu) | (((u32)x.y & 0xFFu) << 8)
                  | (((u32)x.z & 0xFFu) << 16) | (((u32)x.w & 0xFFu) << 24);
            pop += __popc(w);
            u32 c = w, tn;
            tn = p0 & c; p0 ^= c; c = tn;
            tn = p1 & c; p1 ^= c; c = tn;
            tn = p2 & c; p2 ^= c; c = tn;
            tn = p3 & c; p3 ^= c; c = tn;
            tn = p4 & c; p4 ^= c; c = tn;
            p5 ^= c;
        }
        planesA[t] = make_int4((int)p0, (int)p1, (int)p2, (int)p3);  // 16B store
        planesB[t] = make_int2((int)p4, (int)p5);                    // 8B store
    }
    for (int off = 32; off > 0; off >>= 1)
        pop += __shfl_down(pop, off, 64);
    __shared__ u32 sred[4];
    int wid = threadIdx.x >> 6;
    if ((threadIdx.x & 63) == 0) sred[wid] = pop;
    __syncthreads();
    if (threadIdx.x == 0)
        popslot[blockIdx.x] = sred[0] + sred[1] + sred[2] + sred[3];  // no atomic
}

// Kernel 2: planes/weights loads issued FIRST (independent of threshold) so
// their HBM/L2 latency hides under the block-redundant popslot reduction.
// Then bitwise threshold compare across 32 positions at once, XNOR with
// weights, float4 store, per-block mask popcount -> plain slot (parallel
// stores; NO same-address atomics — round 2/3 showed those cost ~9 us).
__global__ __launch_bounds__(256) void k_apply(const int* __restrict__ weights,
                                               const int4* __restrict__ planesA,
                                               const int2* __restrict__ planesB,
                                               const u32* __restrict__ popslot,
                                               const float* __restrict__ vote_p_max,
                                               const int* __restrict__ n_votes_p,
                                               float* __restrict__ out,
                                               u32* __restrict__ maskslot,
                                               int npos, int nblk) {
    int pgs = npos >> 2;
    int t = blockIdx.x * blockDim.x + threadIdx.x;
    // Issue the independent loads up front; consumed only after the threshold
    // phase, so the latency is covered by the reduction below.
    int4 pa, wv; int2 pb;
    if (t < pgs) {
        pa = planesA[t];
        pb = planesB[t];
        wv = ((const int4*)weights)[t];
    }
    __shared__ u32 sred[4];
    __shared__ float s_thresh;
    // block-redundant total: sum popslot[0..nblk) (2KB, L2-hit)
    u32 s = 0;
    for (int i = threadIdx.x; i < nblk; i += blockDim.x) s += popslot[i];
    for (int off = 32; off > 0; off >>= 1) s += __shfl_down(s, off, 64);
    int wid = threadIdx.x >> 6;
    if ((threadIdx.x & 63) == 0) sred[wid] = s;
    __syncthreads();
    if (threadIdx.x == 0) {
        u32 total = sred[0] + sred[1] + sred[2] + sred[3];
        float nv = (float)n_votes_p[0];
        float mean = (float)((double)total / ((double)npos * 8.0));
        s_thresh = fmaxf(vote_p_max[0] * nv, mean);  // == max(p,mean/nv)*nv
    }
    __syncthreads();
    float thresh = s_thresh;
    u32 pop = 0;
    if (t < pgs) {
        int K = (int)floorf(thresh) + 1;   // count > thresh  <=>  count >= K
        if (K < 0) K = 0;
        if (K > 64) K = 64;
        u32 Kp = (u32)(64 - K);            // carry-out of (count + Kp) <=> count >= K
        u32 a0 = (u32)pa.x, a1 = (u32)pa.y, a2 = (u32)pa.z, a3 = (u32)pa.w;
        u32 a4 = (u32)pb.x, a5 = (u32)pb.y;
        u32 carry = (Kp & 1u)  ? a0 : 0u;  // ripple carry, K wave-uniform
        carry = (Kp & 2u)  ? (a1 | carry) : (a1 & carry);
        carry = (Kp & 4u)  ? (a2 | carry) : (a2 & carry);
        carry = (Kp & 8u)  ? (a3 | carry) : (a3 & carry);
        carry = (Kp & 16u) ? (a4 | carry) : (a4 & carry);
        carry = (Kp & 32u) ? (a5 | carry) : (a5 & carry);
        u32 mask = (K == 0) ? 0xFFFFFFFFu : carry;
        u32 ww = ((u32)wv.x & 0xFFu) | (((u32)wv.y & 0xFFu) << 8)
               | (((u32)wv.z & 0xFFu) << 16) | (((u32)wv.w & 0xFFu) << 24);
        u32 xn = ~(ww ^ mask);
        ((float4*)out)[t] = make_float4((float)(xn & 0xFFu),
                                        (float)((xn >> 8) & 0xFFu),
                                        (float)((xn >> 16) & 0xFFu),
                                        (float)((xn >> 24) & 0xFFu));
        pop = __popc(mask);
    }
    for (int off = 32; off > 0; off >>= 1)
        pop += __shfl_down(pop, off, 64);
    __syncthreads();                        // sred reuse
    if ((threadIdx.x & 63) == 0) sred[wid] = pop;
    __syncthreads();
    if (threadIdx.x == 0)
        maskslot[blockIdx.x] = sred[0] + sred[1] + sred[2] + sred[3];
}

// Kernel 3: sum mask-pop slots, write update ratio. Kernel boundary = ordering
// (no atomics anywhere on the critical path).
__global__ __launch_bounds__(256) void k_ratio(const u32* __restrict__ maskslot,
                                               float* __restrict__ out,
                                               int npos, int nblk) {
    __shared__ u32 sred[4];
    u32 s = 0;
    for (int i = threadIdx.x; i < nblk; i += blockDim.x) s += maskslot[i];
    for (int off = 32; off > 0; off >>= 1) s += __shfl_down(s, off, 64);
    int wid = threadIdx.x >> 6;
    if ((threadIdx.x & 63) == 0) sred[wid] = s;
    __syncthreads();
    if (threadIdx.x == 0) {
        u32 mp = sred[0] + sred[1] + sred[2] + sred[3];
        out[npos] = (float)((double)mp / ((double)npos * 8.0));
    }
}

extern "C" void kernel_launch(void* const* d_in, const int* in_sizes, int n_in,
                              void* d_out, int out_size, void* d_ws, size_t ws_size,
                              hipStream_t stream) {
    const int* weights      = (const int*)d_in[0];   // 2048*256 bytes, one per int32
    const int* flip         = (const int*)d_in[1];   // 32*2048*256, one byte per int32
    const int* n_votes_p    = (const int*)d_in[2];
    const float* vote_p_max = (const float*)d_in[3];

    int npos   = in_sizes[0];               // 524288 byte positions
    int nvotes = in_sizes[1] / in_sizes[0]; // 32
    int pgs    = npos / 4;                  // 131072 position groups

    int block = 256;
    int gx = (pgs + block - 1) / block;     // 512 blocks

    // ws layout (no memset needed — all slots fully written before read):
    // [0 .. 4*gx)            popslot
    // [16384 .. )            maskslot (separate cache lines)
    // [65536 .. +2MB)        planesA: int4 per position-group (p0..p3)
    // [+2MB .. +3MB)         planesB: int2 per position-group (p4,p5)
    u32*  popslot  = (u32*)d_ws;
    u32*  maskslot = (u32*)((char*)d_ws + 16384);
    int4* planesA  = (int4*)((char*)d_ws + 65536);
    int2* planesB  = (int2*)((char*)d_ws + 65536 + (size_t)pgs * 16);

    k_count<<<gx, block, 0, stream>>>(flip, planesA, planesB, popslot,
                                      npos, nvotes);
    k_apply<<<gx, block, 0, stream>>>(weights, planesA, planesB, popslot,
                                      vote_p_max, n_votes_p, (float*)d_out,
                                      maskslot, npos, gx);
    k_ratio<<<1, block, 0, stream>>>(maskslot, (float*)d_out, npos, gx);
}